// Round 12
// baseline (114.362 us; speedup 1.0000x reference)
//
#include <hip/hip_runtime.h>
#include <math.h>

#define H 32
#define S 64
#define K 64
#define B 32
#define NTILE 2048
#define NBIGW 4064          // 1024*4 - 32 chain waves
#define SENTU 0x7fc00042u   // qNaN sentinel: chain outputs are never NaN

__device__ __forceinline__ float gelu_f(float x) {
    return 0.5f * x * (1.0f + erff(x * 0.70710678118654752440f));
}

__device__ __forceinline__ void lds_fence() {
    asm volatile("s_waitcnt lgkmcnt(0)" ::: "memory");
}

__device__ __forceinline__ void vm_drain() {
    asm volatile("s_waitcnt vmcnt(0)" ::: "memory");
}

__device__ __forceinline__ float bcast_lane(float v, int lane) {
    return __uint_as_float(__builtin_amdgcn_readlane(__float_as_uint(v), lane));
}

// ws layout (floats):
// [0, 2080)              pe (65 x 32)
// [2080, 67616)          energies (32 x 64 x 32)   (NaN-sentinel re-init per call)
// [67616, 198688)        ennorm (2048 x 64)
// [198688, 200736)       lse (2048)
// [200736, 202784)       tile_ctr (2048 ints)
// [202784]               done_ctr (int)

__global__ void precompute_kernel(float* __restrict__ pe, float* __restrict__ energies,
                                  int* __restrict__ tile_ctr, int* __restrict__ done_ctr) {
    int t = blockIdx.x * 256 + threadIdx.x;
    if (t < B * S * H) energies[t] = __uint_as_float(SENTU);
    if (t < NTILE) tile_ctr[t] = 0;
    if (t == NTILE) done_ctr[0] = 0;
    if (t < 65 * 32) {
        int p = t >> 5, c = t & 31;
        int iq = c >> 1;
        double dt = pow(10000.0, (double)(2 * iq) / 32.0);
        float ang = (float)p * (float)dt;   // f32 rounding matches reference
        double v = (c & 1) ? cos((double)ang) : sin((double)ang);
        pe[t] = (float)v;
    }
}

// 1024 blocks x 256 thr, ALL resident (LB(256,4) -> <=128 VGPR, no spills).
// Blocks 0..31 wave 0: chain (setprio(3), depth-4 prefetch), publishing energies
// via relaxed agent atomics. Remaining 4064 waves: 2 quarter-tiles each, gated by
// NaN-sentinel energies. Completion protocol (relaxed agent atomics + own-queue
// vmcnt drains ONLY -- no cache-invalidating fences): 4th wave of a tile computes
// its logsumexp (fixed order => deterministic); 2048th tile triggers the final
// fixed-order mean.
__global__ __launch_bounds__(256, 4) void fused_kernel(
    const int* __restrict__ neighbor_ids,
    const int* __restrict__ param_indices,
    const float* __restrict__ weights,
    const float* __restrict__ biases,
    const float* __restrict__ node_bias,
    const float* __restrict__ pe_g,
    const float* __restrict__ positions,
    float* energies,
    float* ennorm,
    float* lse,
    int* tile_ctr,
    int* done_ctr,
    float* __restrict__ out) {
    const int bid = blockIdx.x;
    const int tid = threadIdx.x;
    const int wv = tid >> 6;
    const int lane = tid & 63;

    __shared__ int c_idx[S];
    __shared__ float c_pos[S];
    __shared__ float c_pe[(S + 1) * H];
    __shared__ float c_bias[S * H];

    if (bid < 32 && wv == 0) {
        // ================= CHAIN (one wave, b = bid) =================
        __builtin_amdgcn_s_setprio(3);   // protect the serial critical path
        const int b = bid;
        const int l = lane;
        const int r = l >> 5;
        const int d = l & 31;

        c_idx[l] = param_indices[((size_t)(b * S + l)) * K];
        c_pos[l] = positions[l];
        for (int t = l; t < (S + 1) * H; t += 64) c_pe[t] = pe_g[t];
        lds_fence();

        for (int t = l; t < S * H; t += 64)
            c_bias[t] = biases[(size_t)c_idx[t >> 5] * H + (t & 31)];

        float w0[16], w1[16], w2[16], w3[16];
        const int rowoff = r * 16;
        auto loadW = [&](float (&wb)[16], int step) {
            const float* Wp = weights + (size_t)c_idx[step] * (H * H) + (size_t)rowoff * H + d;
            #pragma unroll
            for (int j = 0; j < 16; ++j) wb[j] = Wp[j * H];
        };
        loadW(w0, 0); loadW(w1, 1); loadW(w2, 2); loadW(w3, 3);

        float init_e;
        {
            int nid = neighbor_ids[(size_t)b * S * K * 2];  // [b,0,0,0]
            init_e = gelu_f(0.03125f + node_bias[(size_t)nid * H + d] + c_pe[d]);
        }
        lds_fence();

        float m = -1e30f, ssum = 0.0f, A = 0.0f, nxtprev = 0.0f;

        auto step = [&](float (&wb)[16], int i) {
            float e;
            if (i == 0) {
                e = init_e;
            } else {
                float p = c_pos[i - 1];
                if (p > m) { float sc = expf(m - p); A *= sc; ssum *= sc; m = p; }
                float wgt = expf(p - m);
                A = fmaf(wgt, nxtprev, A);
                ssum += wgt;
                e = A / ssum;
            }
            // publish to L3 (device coherence point); relaxed, no flush, no wait
            if (r == 0)
                __hip_atomic_store(&energies[((size_t)(b * S + i)) * H + d], e,
                                   __ATOMIC_RELAXED, __HIP_MEMORY_SCOPE_AGENT);

            float acc = 0.0f;
            #pragma unroll
            for (int j = 0; j < 16; ++j) {
                float e0 = bcast_lane(e, j);
                float e1 = bcast_lane(e, 16 + j);
                acc = fmaf(r ? e1 : e0, wb[j], acc);
            }
            acc += __shfl_xor(acc, 32, 64);
            nxtprev = gelu_f(acc + c_bias[i * H + d] + c_pe[(i + 1) * H + d]);
            if (i + 4 < S) loadW(wb, i + 4);
        };

        #pragma unroll
        for (int ii = 0; ii < S; ii += 4) {
            step(w0, ii); step(w1, ii + 1); step(w2, ii + 2); step(w3, ii + 3);
        }
    } else {
        // ================= BIG (quarter-tiles, gated) =================
        const int count = (bid < 32) ? (bid + 1) : 32;       // chain waves at/below
        const int rank = bid * 4 + wv - count;                // 0..4063
        const int rowq = lane >> 4;                           // row-phase 0..3
        const int dp = lane & 15;                             // column-pair

        for (int s = rank; s < 4 * NTILE; s += NBIGW) {
            const int i = s >> 7;                             // i-major: ready order
            const int b = (s >> 2) & 31;
            const int quarter = s & 3;
            const int bi = b * S + i;

            // spin until chain published energies(b,i): per-element NaN sentinel
            float ereg[8];
            for (;;) {
                #pragma unroll
                for (int hh = 0; hh < 8; ++hh)
                    ereg[hh] = __hip_atomic_load(&energies[(size_t)bi * H + hh * 4 + rowq],
                                                 __ATOMIC_RELAXED, __HIP_MEMORY_SCOPE_AGENT);
                int bad = 0;
                #pragma unroll
                for (int hh = 0; hh < 8; ++hh) bad |= (ereg[hh] != ereg[hh]);
                if (!__any(bad)) break;
                __builtin_amdgcn_s_sleep(10);   // ~640cy between polls
            }

            float pex = pe_g[(i + 1) * H + 2 * dp];
            float pey = pe_g[(i + 1) * H + 2 * dp + 1];
            int idxv = 0;
            if (lane < 16) idxv = param_indices[(size_t)bi * K + quarter * 16 + lane];

            int ia = __builtin_amdgcn_readlane(idxv, 0);
            int ib = __builtin_amdgcn_readlane(idxv, 8);
            float2 ca[8], cb[8], bca, bcb;
            {
                const float2* Wa = (const float2*)(weights + (size_t)ia * (H * H));
                const float2* Wb = (const float2*)(weights + (size_t)ib * (H * H));
                #pragma unroll
                for (int hh = 0; hh < 8; ++hh) {
                    ca[hh] = Wa[(hh * 4 + rowq) * 16 + dp];
                    cb[hh] = Wb[(hh * 4 + rowq) * 16 + dp];
                }
                bca = *(const float2*)(biases + (size_t)ia * H + 2 * dp);
                bcb = *(const float2*)(biases + (size_t)ib * H + 2 * dp);
            }

            float norm = 0.0f;
            #pragma unroll
            for (int it = 0; it < 8; ++it) {
                float2 na[8], nb[8], bna, bnb;
                if (it < 7) {
                    int ja = __builtin_amdgcn_readlane(idxv, it + 1);
                    int jb = __builtin_amdgcn_readlane(idxv, it + 9);
                    const float2* Wa = (const float2*)(weights + (size_t)ja * (H * H));
                    const float2* Wb = (const float2*)(weights + (size_t)jb * (H * H));
                    #pragma unroll
                    for (int hh = 0; hh < 8; ++hh) {
                        na[hh] = Wa[(hh * 4 + rowq) * 16 + dp];
                        nb[hh] = Wb[(hh * 4 + rowq) * 16 + dp];
                    }
                    bna = *(const float2*)(biases + (size_t)ja * H + 2 * dp);
                    bnb = *(const float2*)(biases + (size_t)jb * H + 2 * dp);
                }

                float axa = 0, aya = 0, axb = 0, ayb = 0;
                #pragma unroll
                for (int hh = 0; hh < 8; ++hh) {
                    axa = fmaf(ereg[hh], ca[hh].x, axa);
                    aya = fmaf(ereg[hh], ca[hh].y, aya);
                    axb = fmaf(ereg[hh], cb[hh].x, axb);
                    ayb = fmaf(ereg[hh], cb[hh].y, ayb);
                }
                axa += __shfl_xor(axa, 16, 64); aya += __shfl_xor(aya, 16, 64);
                axb += __shfl_xor(axb, 16, 64); ayb += __shfl_xor(ayb, 16, 64);
                axa += __shfl_xor(axa, 32, 64); aya += __shfl_xor(aya, 32, 64);
                axb += __shfl_xor(axb, 32, 64); ayb += __shfl_xor(ayb, 32, 64);
                float v0a = gelu_f(axa + bca.x + pex);
                float v1a = gelu_f(aya + bca.y + pey);
                float v0b = gelu_f(axb + bcb.x + pex);
                float v1b = gelu_f(ayb + bcb.y + pey);
                float ssa = fmaf(v0a, v0a, v1a * v1a);
                float ssb = fmaf(v0b, v0b, v1b * v1b);
                #pragma unroll
                for (int mk = 8; mk; mk >>= 1) {
                    ssa += __shfl_xor(ssa, mk, 64);
                    ssb += __shfl_xor(ssb, mk, 64);
                }
                norm = (lane == it)     ? ssa : norm;
                norm = (lane == it + 8) ? ssb : norm;

                if (it < 7) {
                    #pragma unroll
                    for (int hh = 0; hh < 8; ++hh) { ca[hh] = na[hh]; cb[hh] = nb[hh]; }
                    bca = bna; bcb = bnb;
                }
            }
            if (lane < 16)
                __hip_atomic_store(&ennorm[(size_t)bi * K + quarter * 16 + lane],
                                   sqrtf(norm), __ATOMIC_RELAXED, __HIP_MEMORY_SCOPE_AGENT);
            vm_drain();   // own stores at coherence point before signaling

            int old = 0;
            if (lane == 0)
                old = __hip_atomic_fetch_add(&tile_ctr[bi], 1,
                                             __ATOMIC_RELAXED, __HIP_MEMORY_SCOPE_AGENT);
            old = __shfl(old, 0, 64);

            if (old == 3) {
                // 4th arriver: tile logsumexp, fixed order -> deterministic
                float en = __hip_atomic_load(&ennorm[(size_t)bi * K + lane],
                                             __ATOMIC_RELAXED, __HIP_MEMORY_SCOPE_AGENT);
                float mm = en;
                #pragma unroll
                for (int mk = 32; mk; mk >>= 1) mm = fmaxf(mm, __shfl_xor(mm, mk, 64));
                float sx = expf(en - mm);
                #pragma unroll
                for (int mk = 32; mk; mk >>= 1) sx += __shfl_xor(sx, mk, 64);
                float en0 = bcast_lane(en, 0);
                if (lane == 0)
                    __hip_atomic_store(&lse[bi], mm + logf(sx) - en0,
                                       __ATOMIC_RELAXED, __HIP_MEMORY_SCOPE_AGENT);
                vm_drain();

                int old2 = 0;
                if (lane == 0)
                    old2 = __hip_atomic_fetch_add(done_ctr, 1,
                                                  __ATOMIC_RELAXED, __HIP_MEMORY_SCOPE_AGENT);
                old2 = __shfl(old2, 0, 64);

                if (old2 == NTILE - 1) {
                    // final fixed-order mean over 2048 tile results
                    float fsum = 0.0f;
                    for (int j = 0; j < 32; ++j)
                        fsum += __hip_atomic_load(&lse[lane + 64 * j],
                                                  __ATOMIC_RELAXED, __HIP_MEMORY_SCOPE_AGENT);
                    #pragma unroll
                    for (int mk = 32; mk; mk >>= 1) fsum += __shfl_xor(fsum, mk, 64);
                    if (lane == 0) out[0] = fsum * (1.0f / 2048.0f);
                }
            }
        }
    }
}

extern "C" void kernel_launch(void* const* d_in, const int* in_sizes, int n_in,
                              void* d_out, int out_size, void* d_ws, size_t ws_size,
                              hipStream_t stream) {
    const int*   neighbor_ids  = (const int*)d_in[0];
    const int*   param_indices = (const int*)d_in[1];
    const float* weights       = (const float*)d_in[2];
    const float* biases        = (const float*)d_in[3];
    const float* node_bias     = (const float*)d_in[4];
    const float* positions     = (const float*)d_in[5];

    float* ws       = (float*)d_ws;
    float* pe       = ws;                      // 2080
    float* energies = ws + 2080;               // 65536
    float* ennorm   = ws + 67616;              // 131072
    float* lse      = ws + 198688;             // 2048
    int*   tile_ctr = (int*)(ws + 200736);     // 2048
    int*   done_ctr = (int*)(ws + 202784);     // 1

    hipLaunchKernelGGL(precompute_kernel, dim3(256), dim3(256), 0, stream,
                       pe, energies, tile_ctr, done_ctr);
    hipLaunchKernelGGL(fused_kernel, dim3(1024), dim3(256), 0, stream,
                       neighbor_ids, param_indices, weights, biases, node_bias,
                       pe, positions, energies, ennorm, lse, tile_ctr, done_ctr,
                       (float*)d_out);
}

// Round 13
// 110.768 us; speedup vs baseline: 1.0325x; 1.0325x over previous
//
#include <hip/hip_runtime.h>
#include <math.h>

#define H 32
#define S 64
#define K 64
#define B 32
#define NTILE 2048
#define NBIGW 4064          // 1024*4 - 32 chain waves
#define SENTU 0x7fc00042u   // qNaN sentinel: chain outputs are never NaN

__device__ __forceinline__ float gelu_f(float x) {
    return 0.5f * x * (1.0f + erff(x * 0.70710678118654752440f));
}

__device__ __forceinline__ void lds_fence() {
    asm volatile("s_waitcnt lgkmcnt(0)" ::: "memory");
}

__device__ __forceinline__ void vm_drain() {
    asm volatile("s_waitcnt vmcnt(0)" ::: "memory");
}

__device__ __forceinline__ float bcast_lane(float v, int lane) {
    return __uint_as_float(__builtin_amdgcn_readlane(__float_as_uint(v), lane));
}

// ws layout (floats):
// [0, 2080)              pe (65 x 32)
// [2080, 67616)          energies (32 x 64 x 32)   (NaN-sentinel re-init per call)
// [67616, 198688)        ennorm (2048 x 64)
// [198688, 198720)       partials (32)
// [198720]               done_ctr (int)

__global__ void precompute_kernel(float* __restrict__ pe, float* __restrict__ energies,
                                  int* __restrict__ done_ctr) {
    int t = blockIdx.x * 256 + threadIdx.x;
    if (t < B * S * H) energies[t] = __uint_as_float(SENTU);
    if (t == 0) done_ctr[0] = 0;
    if (t < 65 * 32) {
        int p = t >> 5, c = t & 31;
        int iq = c >> 1;
        double dt = pow(10000.0, (double)(2 * iq) / 32.0);
        float ang = (float)p * (float)dt;   // f32 rounding matches reference
        double v = (c & 1) ? cos((double)ang) : sin((double)ang);
        pe[t] = (float)v;
    }
}

// 1024 blocks x 256 thr, ALL resident (LB(256,4) -> <=128 VGPR, no spills).
// Blocks 0..31 wave 0: chain (setprio(3), depth-4 W prefetch, bias/pe/pos
// register-rotated one step ahead so LDS latency is off the serial path).
// Remaining 4064 waves: 2 quarter-tiles each, gated by NaN-sentinel energies.
__global__ __launch_bounds__(256, 4) void fused_kernel(
    const int* __restrict__ neighbor_ids,
    const int* __restrict__ param_indices,
    const float* __restrict__ weights,
    const float* __restrict__ biases,
    const float* __restrict__ node_bias,
    const float* __restrict__ pe_g,
    const float* __restrict__ positions,
    float* energies,
    float* __restrict__ ennorm) {
    const int bid = blockIdx.x;
    const int tid = threadIdx.x;
    const int wv = tid >> 6;
    const int lane = tid & 63;

    __shared__ int c_idx[S];
    __shared__ float c_pos[S];
    __shared__ float c_pe[(S + 1) * H];
    __shared__ float c_bias[S * H];

    if (bid < 32 && wv == 0) {
        // ================= CHAIN (one wave, b = bid) =================
        __builtin_amdgcn_s_setprio(3);   // protect the serial critical path
        const int b = bid;
        const int l = lane;
        const int r = l >> 5;
        const int d = l & 31;

        c_idx[l] = param_indices[((size_t)(b * S + l)) * K];
        c_pos[l] = positions[l];
        for (int t = l; t < (S + 1) * H; t += 64) c_pe[t] = pe_g[t];
        lds_fence();

        for (int t = l; t < S * H; t += 64)
            c_bias[t] = biases[(size_t)c_idx[t >> 5] * H + (t & 31)];

        float w0[16], w1[16], w2[16], w3[16];
        const int rowoff = r * 16;
        auto loadW = [&](float (&wb)[16], int step) {
            const float* Wp = weights + (size_t)c_idx[step] * (H * H) + (size_t)rowoff * H + d;
            #pragma unroll
            for (int j = 0; j < 16; ++j) wb[j] = Wp[j * H];
        };
        loadW(w0, 0); loadW(w1, 1); loadW(w2, 2); loadW(w3, 3);

        float init_e;
        {
            int nid = neighbor_ids[(size_t)b * S * K * 2];  // [b,0,0,0]
            init_e = gelu_f(0.03125f + node_bias[(size_t)nid * H + d] + c_pe[d]);
        }
        lds_fence();

        float m = -1e30f, ssum = 0.0f, A = 0.0f, nxtprev = 0.0f;

        // register-rotated step constants (loaded one step ahead)
        float cur_bias = c_bias[d];            // bias[0]
        float cur_pe   = c_pe[H + d];          // pe[1]
        float cur_pos  = c_pos[0];             // pos used at step 1

        auto step = [&](float (&wb)[16], int i) {
            // issue next step's LDS reads NOW (full step to complete)
            float nb_bias = (i + 1 < S) ? c_bias[(i + 1) * H + d] : 0.0f;
            float nb_pe   = (i + 2 <= S) ? c_pe[(i + 2 <= S ? i + 2 : S) * H + d] : 0.0f;
            float nb_pos  = (i + 1 < S) ? c_pos[i] : 0.0f;

            float e;
            if (i == 0) {
                e = init_e;
            } else {
                float p = cur_pos;
                if (p > m) { float sc = expf(m - p); A *= sc; ssum *= sc; m = p; }
                float wgt = expf(p - m);
                A = fmaf(wgt, nxtprev, A);
                ssum += wgt;
                e = A / ssum;
            }
            // publish to L3 (device coherence point); relaxed, no flush, no wait
            if (r == 0)
                __hip_atomic_store(&energies[((size_t)(b * S + i)) * H + d], e,
                                   __ATOMIC_RELAXED, __HIP_MEMORY_SCOPE_AGENT);

            float acc = 0.0f;
            #pragma unroll
            for (int j = 0; j < 16; ++j) {
                float e0 = bcast_lane(e, j);
                float e1 = bcast_lane(e, 16 + j);
                acc = fmaf(r ? e1 : e0, wb[j], acc);
            }
            acc += __shfl_xor(acc, 32, 64);
            nxtprev = gelu_f(acc + cur_bias + cur_pe);
            if (i + 4 < S) loadW(wb, i + 4);

            cur_bias = nb_bias; cur_pe = nb_pe; cur_pos = nb_pos;
        };

        #pragma unroll
        for (int ii = 0; ii < S; ii += 4) {
            step(w0, ii); step(w1, ii + 1); step(w2, ii + 2); step(w3, ii + 3);
        }
    } else {
        // ================= BIG (quarter-tiles, gated) =================
        const int count = (bid < 32) ? (bid + 1) : 32;       // chain waves at/below
        const int rank = bid * 4 + wv - count;                // 0..4063
        const int rowq = lane >> 4;                           // row-phase 0..3
        const int dp = lane & 15;                             // column-pair

        for (int s = rank; s < 4 * NTILE; s += NBIGW) {
            const int i = s >> 7;                             // i-major: ready order
            const int b = (s >> 2) & 31;
            const int quarter = s & 3;
            const int bi = b * S + i;

            // spin until chain published energies(b,i): per-element NaN sentinel
            float ereg[8];
            for (;;) {
                #pragma unroll
                for (int hh = 0; hh < 8; ++hh)
                    ereg[hh] = __hip_atomic_load(&energies[(size_t)bi * H + hh * 4 + rowq],
                                                 __ATOMIC_RELAXED, __HIP_MEMORY_SCOPE_AGENT);
                int bad = 0;
                #pragma unroll
                for (int hh = 0; hh < 8; ++hh) bad |= (ereg[hh] != ereg[hh]);
                if (!__any(bad)) break;
                __builtin_amdgcn_s_sleep(10);   // ~640cy between polls
            }

            float pex = pe_g[(i + 1) * H + 2 * dp];
            float pey = pe_g[(i + 1) * H + 2 * dp + 1];
            int idxv = 0;
            if (lane < 16) idxv = param_indices[(size_t)bi * K + quarter * 16 + lane];

            int ia = __builtin_amdgcn_readlane(idxv, 0);
            int ib = __builtin_amdgcn_readlane(idxv, 8);
            float2 ca[8], cb[8], bca, bcb;
            {
                const float2* Wa = (const float2*)(weights + (size_t)ia * (H * H));
                const float2* Wb = (const float2*)(weights + (size_t)ib * (H * H));
                #pragma unroll
                for (int hh = 0; hh < 8; ++hh) {
                    ca[hh] = Wa[(hh * 4 + rowq) * 16 + dp];
                    cb[hh] = Wb[(hh * 4 + rowq) * 16 + dp];
                }
                bca = *(const float2*)(biases + (size_t)ia * H + 2 * dp);
                bcb = *(const float2*)(biases + (size_t)ib * H + 2 * dp);
            }

            float norm = 0.0f;
            #pragma unroll
            for (int it = 0; it < 8; ++it) {
                float2 na[8], nb[8], bna, bnb;
                if (it < 7) {
                    int ja = __builtin_amdgcn_readlane(idxv, it + 1);
                    int jb = __builtin_amdgcn_readlane(idxv, it + 9);
                    const float2* Wa = (const float2*)(weights + (size_t)ja * (H * H));
                    const float2* Wb = (const float2*)(weights + (size_t)jb * (H * H));
                    #pragma unroll
                    for (int hh = 0; hh < 8; ++hh) {
                        na[hh] = Wa[(hh * 4 + rowq) * 16 + dp];
                        nb[hh] = Wb[(hh * 4 + rowq) * 16 + dp];
                    }
                    bna = *(const float2*)(biases + (size_t)ja * H + 2 * dp);
                    bnb = *(const float2*)(biases + (size_t)jb * H + 2 * dp);
                }

                float axa = 0, aya = 0, axb = 0, ayb = 0;
                #pragma unroll
                for (int hh = 0; hh < 8; ++hh) {
                    axa = fmaf(ereg[hh], ca[hh].x, axa);
                    aya = fmaf(ereg[hh], ca[hh].y, aya);
                    axb = fmaf(ereg[hh], cb[hh].x, axb);
                    ayb = fmaf(ereg[hh], cb[hh].y, ayb);
                }
                axa += __shfl_xor(axa, 16, 64); aya += __shfl_xor(aya, 16, 64);
                axb += __shfl_xor(axb, 16, 64); ayb += __shfl_xor(ayb, 16, 64);
                axa += __shfl_xor(axa, 32, 64); aya += __shfl_xor(aya, 32, 64);
                axb += __shfl_xor(axb, 32, 64); ayb += __shfl_xor(ayb, 32, 64);
                float v0a = gelu_f(axa + bca.x + pex);
                float v1a = gelu_f(aya + bca.y + pey);
                float v0b = gelu_f(axb + bcb.x + pex);
                float v1b = gelu_f(ayb + bcb.y + pey);
                float ssa = fmaf(v0a, v0a, v1a * v1a);
                float ssb = fmaf(v0b, v0b, v1b * v1b);
                #pragma unroll
                for (int mk = 8; mk; mk >>= 1) {
                    ssa += __shfl_xor(ssa, mk, 64);
                    ssb += __shfl_xor(ssb, mk, 64);
                }
                norm = (lane == it)     ? ssa : norm;
                norm = (lane == it + 8) ? ssb : norm;

                if (it < 7) {
                    #pragma unroll
                    for (int hh = 0; hh < 8; ++hh) { ca[hh] = na[hh]; cb[hh] = nb[hh]; }
                    bca = bna; bcb = bnb;
                }
            }
            if (lane < 16)
                ennorm[(size_t)bi * K + quarter * 16 + lane] = sqrtf(norm);
        }
    }
}

// 32 blocks x 4 waves x 16 tiles: per-tile logsumexp + per-block sum, with the
// final 32-partial sum done by the last block (relaxed atomics + own vm_drain
// only -- no cache-invalidating fences; 32 blocks -> negligible cost).
__global__ __launch_bounds__(256) void reduce_kernel(const float* __restrict__ ennorm,
                                                     float* partials,
                                                     int* done_ctr,
                                                     float* __restrict__ out) {
    int bid = blockIdx.x;
    int tid = threadIdx.x;
    int wv = tid >> 6;
    int lane = tid & 63;
    __shared__ float sh[4];
    __shared__ int amLast;

    float wsum = 0.0f;
    for (int j = 0; j < 16; ++j) {
        int t = bid * 64 + wv * 16 + j;
        float en = ennorm[(size_t)t * K + lane];
        float mm = en;
        #pragma unroll
        for (int mk = 32; mk; mk >>= 1) mm = fmaxf(mm, __shfl_xor(mm, mk, 64));
        float sx = expf(en - mm);
        #pragma unroll
        for (int mk = 32; mk; mk >>= 1) sx += __shfl_xor(sx, mk, 64);
        float en0 = bcast_lane(en, 0);
        wsum += mm + logf(sx) - en0;
    }
    if (lane == 0) sh[wv] = wsum;
    __syncthreads();
    if (tid == 0) {
        __hip_atomic_store(&partials[bid], (sh[0] + sh[1]) + (sh[2] + sh[3]),
                           __ATOMIC_RELAXED, __HIP_MEMORY_SCOPE_AGENT);
        vm_drain();   // own store visible at L3 before signaling
        int old = __hip_atomic_fetch_add(done_ctr, 1,
                                         __ATOMIC_RELAXED, __HIP_MEMORY_SCOPE_AGENT);
        amLast = (old == 31);
    }
    __syncthreads();
    if (amLast && tid < 32) {
        float v = __hip_atomic_load(&partials[tid],
                                    __ATOMIC_RELAXED, __HIP_MEMORY_SCOPE_AGENT);
        // fixed-order serial sum in lane 0 -> deterministic
        if (tid == 0) {
            float s = v;
            for (int j = 1; j < 32; ++j)
                s += __hip_atomic_load(&partials[j],
                                       __ATOMIC_RELAXED, __HIP_MEMORY_SCOPE_AGENT);
            out[0] = s * (1.0f / 2048.0f);
        }
    }
}

extern "C" void kernel_launch(void* const* d_in, const int* in_sizes, int n_in,
                              void* d_out, int out_size, void* d_ws, size_t ws_size,
                              hipStream_t stream) {
    const int*   neighbor_ids  = (const int*)d_in[0];
    const int*   param_indices = (const int*)d_in[1];
    const float* weights       = (const float*)d_in[2];
    const float* biases        = (const float*)d_in[3];
    const float* node_bias     = (const float*)d_in[4];
    const float* positions     = (const float*)d_in[5];

    float* ws       = (float*)d_ws;
    float* pe       = ws;                      // 2080
    float* energies = ws + 2080;               // 65536
    float* ennorm   = ws + 67616;              // 131072
    float* partials = ws + 198688;             // 32
    int*   done_ctr = (int*)(ws + 198720);     // 1

    hipLaunchKernelGGL(precompute_kernel, dim3(256), dim3(256), 0, stream,
                       pe, energies, done_ctr);
    hipLaunchKernelGGL(fused_kernel, dim3(1024), dim3(256), 0, stream,
                       neighbor_ids, param_indices, weights, biases, node_bias,
                       pe, positions, energies, ennorm);
    hipLaunchKernelGGL(reduce_kernel, dim3(32), dim3(256), 0, stream,
                       ennorm, partials, done_ctr, (float*)d_out);
}